// Round 12
// baseline (231.252 us; speedup 1.0000x reference)
//
#include <hip/hip_runtime.h>
#include <math.h>

#define NPTS   8192
#define NB     128
#define TOPKN  20
#define NSAMP  100
#define NPROB  (NB + NB + NB * NSAMP)   // 13056 = 204*64 exactly
#define SQRT2C 1.4142

// output element offsets (float32)
#define OFF_OUT  0
#define OFF_RES  1152
#define OFF_OUTK 1049728
#define OFF_RESK 1050880
#define OFF_OUTS 1053440
#define OFF_WACC 1168640

// workspace byte offsets (SoA: G[45][NPROB], Tp[6][NPROB], v[9][NPROB])
#define WS_G    0
#define WS_TP   4700160
#define WS_V    5326848
#define WS_TOPK 6266880

// upper-triangle index for 9x9
__device__ __forceinline__ constexpr int tri9(int i, int j) {
  int a = i < j ? i : j;
  int b = i < j ? j : i;
  return a * 9 - a * (a - 1) / 2 + (b - a);
}

// --------------------------------------------- K1: prep (topk ∥ main G)
__global__ __launch_bounds__(1024) void prep_kernel(
    const float* __restrict__ pts1, const float* __restrict__ pts2,
    const float* __restrict__ wv, const int* __restrict__ un,
    int* __restrict__ topkidx, double* __restrict__ Gall,
    double* __restrict__ Tpall) {
  __shared__ float sw[NPTS];
  __shared__ float r16a[16], r16b[16], r16c[16], r16d[16];
  __shared__ int   i16[16];
  __shared__ double sred[16][45];
  __shared__ float sbc[6];
  const int tid = threadIdx.x, lane = tid & 63, wid = tid >> 6;

  if (blockIdx.x < NB) {
    const int b = blockIdx.x;
    const int m = un[b];
    const int mlim = (m + 1023) & ~1023;
    for (int n = tid; n < mlim; n += 1024)
      sw[n] = (n < m) ? wv[(size_t)b * NPTS + n] : -INFINITY;
    __syncthreads();
    for (int k = 0; k < TOPKN; ++k) {
      float best = -INFINITY; int bi = 0x7fffffff;
      for (int n = tid; n < mlim; n += 1024) {
        float v = sw[n];
        if (v > best) { best = v; bi = n; }
      }
      #pragma unroll
      for (int off = 32; off > 0; off >>= 1) {
        float ov = __shfl_down(best, off);
        int   oi = __shfl_down(bi, off);
        if (ov > best || (ov == best && oi < bi)) { best = ov; bi = oi; }
      }
      if (lane == 0) { r16a[wid] = best; i16[wid] = bi; }
      __syncthreads();
      if (wid == 0) {
        float v = (lane < 16) ? r16a[lane] : -INFINITY;
        int  ix = (lane < 16) ? i16[lane] : 0x7fffffff;
        #pragma unroll
        for (int off = 8; off > 0; off >>= 1) {
          float ov = __shfl_down(v, off);
          int   oi = __shfl_down(ix, off);
          if (ov > v || (ov == v && oi < ix)) { v = ov; ix = oi; }
        }
        if (lane == 0) { topkidx[b * TOPKN + k] = ix; sw[ix] = -INFINITY; }
      }
      __syncthreads();
    }
    return;
  }

  // ---------------- stats + Gram (f32, register-staged) ----------------
  const int b = blockIdx.x - NB;
  const float* P1 = pts1 + (size_t)b * NPTS * 3;
  const float* P2 = pts2 + (size_t)b * NPTS * 3;
  const float* W  = wv   + (size_t)b * NPTS;

  float x1[8], y1[8], x2[8], y2[8], ww8[8];
  #pragma unroll
  for (int i = 0; i < 8; ++i) {
    const int n = tid + i * 1024;
    x1[i] = P1[n * 3]; y1[i] = P1[n * 3 + 1];
    x2[i] = P2[n * 3]; y2[i] = P2[n * 3 + 1];
    ww8[i] = W[n];
  }

  float sx1 = 0, sy1 = 0, sx2 = 0, sy2 = 0;
  #pragma unroll
  for (int i = 0; i < 8; ++i) { sx1 += x1[i]; sy1 += y1[i]; sx2 += x2[i]; sy2 += y2[i]; }
  #pragma unroll
  for (int off = 32; off > 0; off >>= 1) {
    sx1 += __shfl_down(sx1, off); sy1 += __shfl_down(sy1, off);
    sx2 += __shfl_down(sx2, off); sy2 += __shfl_down(sy2, off);
  }
  if (lane == 0) { r16a[wid] = sx1; r16b[wid] = sy1; r16c[wid] = sx2; r16d[wid] = sy2; }
  __syncthreads();
  if (wid == 0) {
    float a = (lane < 16) ? r16a[lane] : 0.f;
    float bb = (lane < 16) ? r16b[lane] : 0.f;
    float c = (lane < 16) ? r16c[lane] : 0.f;
    float d = (lane < 16) ? r16d[lane] : 0.f;
    #pragma unroll
    for (int off = 8; off > 0; off >>= 1) {
      a += __shfl_down(a, off); bb += __shfl_down(bb, off);
      c += __shfl_down(c, off); d += __shfl_down(d, off);
    }
    if (lane == 0) {
      sbc[0] = a / NPTS; sbc[1] = bb / NPTS; sbc[2] = c / NPTS; sbc[3] = d / NPTS;
    }
  }
  __syncthreads();
  const float cx1 = sbc[0], cy1 = sbc[1], cx2 = sbc[2], cy2 = sbc[3];

  float d1 = 0, d2 = 0;
  #pragma unroll
  for (int i = 0; i < 8; ++i) {
    float ax = x1[i] - cx1, ay = y1[i] - cy1;
    float bx = x2[i] - cx2, by = y2[i] - cy2;
    d1 += sqrtf(ax * ax + ay * ay);
    d2 += sqrtf(bx * bx + by * by);
  }
  #pragma unroll
  for (int off = 32; off > 0; off >>= 1) { d1 += __shfl_down(d1, off); d2 += __shfl_down(d2, off); }
  __syncthreads();
  if (lane == 0) { r16a[wid] = d1; r16b[wid] = d2; }
  __syncthreads();
  if (wid == 0) {
    float a = (lane < 16) ? r16a[lane] : 0.f;
    float bb = (lane < 16) ? r16b[lane] : 0.f;
    #pragma unroll
    for (int off = 8; off > 0; off >>= 1) { a += __shfl_down(a, off); bb += __shfl_down(bb, off); }
    if (lane == 0) {
      sbc[4] = (float)SQRT2C / (a / NPTS);
      sbc[5] = (float)SQRT2C / (bb / NPTS);
    }
  }
  __syncthreads();
  const float s1 = sbc[4], s2 = sbc[5];

  float g[45];
  #pragma unroll
  for (int i = 0; i < 45; ++i) g[i] = 0.f;
  #pragma unroll
  for (int i = 0; i < 8; ++i) {
    float p1x = s1 * (x1[i] - cx1), p1y = s1 * (y1[i] - cy1);
    float p2x = s2 * (x2[i] - cx2), p2y = s2 * (y2[i] - cy2);
    float f[9] = { p2x * p1x, p2x * p1y, p2x,
                   p2y * p1x, p2y * p1y, p2y,
                   p1x, p1y, 1.f };
    float n2 = 0.f;
    #pragma unroll
    for (int j = 0; j < 9; ++j) n2 += f[j] * f[j];
    float sc = ww8[i] / sqrtf(n2);
    #pragma unroll
    for (int j = 0; j < 9; ++j) f[j] *= sc;
    int t = 0;
    #pragma unroll
    for (int a = 0; a < 9; ++a)
      #pragma unroll
      for (int c = a; c < 9; ++c) { g[t] += f[a] * f[c]; ++t; }
  }
  #pragma unroll
  for (int t = 0; t < 45; ++t) {
    float v = g[t];
    #pragma unroll
    for (int off = 32; off > 0; off >>= 1) v += __shfl_down(v, off);
    if (lane == 0) sred[wid][t] = (double)v;
  }
  __syncthreads();
  if (tid < 45) {
    double a = 0;
    #pragma unroll
    for (int w = 0; w < 16; ++w) a += sred[w][tid];
    Gall[(size_t)tid * NPROB + b] = a;
  }
  if (tid == 0) {
    Tpall[0 * NPROB + b] = (double)s1;  Tpall[1 * NPROB + b] = (double)cx1;
    Tpall[2 * NPROB + b] = (double)cy1; Tpall[3 * NPROB + b] = (double)s2;
    Tpall[4 * NPROB + b] = (double)cx2; Tpall[5 * NPROB + b] = (double)cy2;
  }
}

// ------------------------------------------------- K2: small (20-pt) problems
__global__ __launch_bounds__(256) void small_g_kernel(
    const float* __restrict__ pts1, const float* __restrict__ pts2,
    const float* __restrict__ wv, const int* __restrict__ topkidx,
    const int* __restrict__ sampled, double* __restrict__ Gall,
    double* __restrict__ Tpall) {
  const int p = blockIdx.x * blockDim.x + threadIdx.x;
  if (p >= NB + NB * NSAMP) return;
  const int prob = NB + p;
  int b; const int* idx;
  if (p < NB) { b = p; idx = topkidx + p * TOPKN; }
  else { int q = p - NB; b = q / NSAMP; idx = sampled + (size_t)q * TOPKN; }
  const float* P1 = pts1 + (size_t)b * NPTS * 3;
  const float* P2 = pts2 + (size_t)b * NPTS * 3;
  const float* W  = wv   + (size_t)b * NPTS;

  float x1[TOPKN], y1[TOPKN], x2[TOPKN], y2[TOPKN], ww[TOPKN];
  #pragma unroll
  for (int k = 0; k < TOPKN; ++k) {
    int n = idx[k];
    x1[k] = P1[n * 3]; y1[k] = P1[n * 3 + 1];
    x2[k] = P2[n * 3]; y2[k] = P2[n * 3 + 1];
    ww[k] = W[n];
  }
  float cx1 = 0, cy1 = 0, cx2 = 0, cy2 = 0;
  #pragma unroll
  for (int k = 0; k < TOPKN; ++k) { cx1 += x1[k]; cy1 += y1[k]; cx2 += x2[k]; cy2 += y2[k]; }
  cx1 /= TOPKN; cy1 /= TOPKN; cx2 /= TOPKN; cy2 /= TOPKN;
  float d1 = 0, d2 = 0;
  #pragma unroll
  for (int k = 0; k < TOPKN; ++k) {
    float ax = x1[k] - cx1, ay = y1[k] - cy1; d1 += sqrtf(ax * ax + ay * ay);
    float bx = x2[k] - cx2, by = y2[k] - cy2; d2 += sqrtf(bx * bx + by * by);
  }
  const float s1 = (float)SQRT2C / (d1 / TOPKN), s2 = (float)SQRT2C / (d2 / TOPKN);

  float g[45];
  #pragma unroll
  for (int i = 0; i < 45; ++i) g[i] = 0.f;
  #pragma unroll
  for (int k = 0; k < TOPKN; ++k) {
    float p1x = s1 * (x1[k] - cx1), p1y = s1 * (y1[k] - cy1);
    float p2x = s2 * (x2[k] - cx2), p2y = s2 * (y2[k] - cy2);
    float f[9] = { p2x * p1x, p2x * p1y, p2x,
                   p2y * p1x, p2y * p1y, p2y,
                   p1x, p1y, 1.f };
    float n2 = 0.f;
    #pragma unroll
    for (int i = 0; i < 9; ++i) n2 += f[i] * f[i];
    float sc = ww[k] / sqrtf(n2);
    #pragma unroll
    for (int i = 0; i < 9; ++i) f[i] *= sc;
    int t = 0;
    #pragma unroll
    for (int i = 0; i < 9; ++i)
      #pragma unroll
      for (int j = i; j < 9; ++j) { g[t] += f[i] * f[j]; ++t; }
  }
  #pragma unroll
  for (int i = 0; i < 45; ++i) Gall[(size_t)i * NPROB + prob] = (double)g[i];
  Tpall[0 * NPROB + prob] = (double)s1;  Tpall[1 * NPROB + prob] = (double)cx1;
  Tpall[2 * NPROB + prob] = (double)cy1; Tpall[3 * NPROB + prob] = (double)s2;
  Tpall[4 * NPROB + prob] = (double)cx2; Tpall[5 * NPROB + prob] = (double)cy2;
}

// ---------------------------------------------------------------- K3: solve
// Wave-split Jacobi: block = 128 thr = 2 waves over the SAME 64 problems.
// Wave 0 (A-role) owns g[45]/problem and computes rotation params + A update;
// wave 1 (V-role) owns Vf[9][9]/problem and applies (c,s) from LDS. The two
// updates run concurrently on different SIMDs -> 2x waves, 1/2 work per wave
// (the lane-interleaved alternative would serialize under exec-masking).
// Skipped rotations are branchless identities (t=0,c=1,s=0) so V never
// diverges and A's update is exact.
__global__ __launch_bounds__(128, 1) void solve_kernel(
    const double* __restrict__ Gall, const double* __restrict__ Tpall,
    double* __restrict__ vall, float* __restrict__ dout) {
  __shared__ float csC[64], csS[64];
  __shared__ int   imins[64];
  const int tid = threadIdx.x;
  const int pid = tid & 63;
  const int role = tid >> 6;               // 0 = A-wave, 1 = V-wave
  const int prob = blockIdx.x * 64 + pid;  // NPROB = 204*64 exactly

  float g[45];
  float Vf[9][9];
  if (role == 0) {
    #pragma unroll
    for (int i = 0; i < 45; ++i) g[i] = (float)Gall[(size_t)i * NPROB + prob];
  } else {
    #pragma unroll
    for (int i = 0; i < 9; ++i)
      #pragma unroll
      for (int j = 0; j < 9; ++j) Vf[i][j] = (i == j) ? 1.0f : 0.0f;
  }

  for (int sweep = 0; sweep < 5; ++sweep) {
    #pragma unroll
    for (int p = 0; p < 9; ++p) {
      #pragma unroll
      for (int q = p + 1; q < 9; ++q) {
        float apq = 0.f, app = 0.f, aqq = 0.f;
        float cf = 1.f, sf = 0.f, tf = 0.f, tauf = 0.f;
        if (role == 0) {
          apq = g[tri9(p, q)];
          app = g[tri9(p, p)];
          aqq = g[tri9(q, q)];
          if (fabsf(apq) > 1e-30f) {
            float thf = (aqq - app) / (2.0f * apq);
            tf = 1.0f / (fabsf(thf) + sqrtf(1.0f + thf * thf));
            if (thf < 0.0f) tf = -tf;
            cf = 1.0f / sqrtf(1.0f + tf * tf);
            sf = tf * cf;
            tauf = sf / (1.0f + cf);
          }
          csC[pid] = cf; csS[pid] = sf;
        }
        __syncthreads();
        if (role == 0) {
          g[tri9(p, p)] = app - tf * apq;
          g[tri9(q, q)] = aqq + tf * apq;
          g[tri9(p, q)] = 0.0f;
          #pragma unroll
          for (int k = 0; k < 9; ++k) {
            if (k != p && k != q) {
              float akp = g[tri9(k, p)], akq = g[tri9(k, q)];
              g[tri9(k, p)] = akp - sf * (akq + tauf * akp);
              g[tri9(k, q)] = akq + sf * (akp - tauf * akq);
            }
          }
        } else {
          float c2 = csC[pid], s2 = csS[pid];
          #pragma unroll
          for (int k = 0; k < 9; ++k) {
            float a = Vf[k][p], b2 = Vf[k][q];
            Vf[k][p] = c2 * a - s2 * b2;
            Vf[k][q] = s2 * a + c2 * b2;
          }
        }
        __syncthreads();
      }
    }
  }

  // A-wave publishes argmin eigenvalue, then exits.
  if (role == 0) {
    int imin = 0; float emin = g[tri9(0, 0)];
    #pragma unroll
    for (int i = 1; i < 9; ++i) {
      float d = g[tri9(i, i)];
      if (d < emin) { emin = d; imin = i; }
    }
    imins[pid] = imin;
  }
  __syncthreads();
  if (role == 0) return;

  // ---------------- V-wave epilogue ----------------
  const int imin = imins[pid];
  double v[9];
  #pragma unroll
  for (int k = 0; k < 9; ++k) v[k] = (double)Vf[k][0];
  #pragma unroll
  for (int j = 1; j < 9; ++j) {
    bool take = (j == imin);
    #pragma unroll
    for (int k = 0; k < 9; ++k) v[k] = take ? (double)Vf[k][j] : v[k];
  }
  {
    double n2 = 0;
    #pragma unroll
    for (int i = 0; i < 9; ++i) n2 += v[i] * v[i];
    double inv = 1.0 / sqrt(n2);
    #pragma unroll
    for (int i = 0; i < 9; ++i) v[i] *= inv;
  }
  int imax = 0; double amax = fabs(v[0]);
  #pragma unroll
  for (int i = 1; i < 9; ++i) { double a = fabs(v[i]); if (a > amax) { amax = a; imax = i; } }
  double vmax = v[0];
  #pragma unroll
  for (int i = 1; i < 9; ++i) vmax = (i == imax) ? v[i] : vmax;
  double sgn = (vmax > 0.0) ? 1.0 : ((vmax < 0.0) ? -1.0 : 0.0);
  #pragma unroll
  for (int i = 0; i < 9; ++i) v[i] *= sgn;

  #pragma unroll
  for (int i = 0; i < 9; ++i) vall[(size_t)i * NPROB + prob] = v[i];

  // rank-2 projection via f32 3x3 Jacobi on M = F^T F (entries <= 1)
  double F[3][3] = { { v[0], v[1], v[2] }, { v[3], v[4], v[5] }, { v[6], v[7], v[8] } };
  float M[3][3];
  #pragma unroll
  for (int i = 0; i < 3; ++i)
    #pragma unroll
    for (int j = 0; j < 3; ++j) {
      double acc = 0;
      #pragma unroll
      for (int k = 0; k < 3; ++k) acc += F[k][i] * F[k][j];
      M[i][j] = (float)acc;
    }
  float W3[3][3] = { { 1, 0, 0 }, { 0, 1, 0 }, { 0, 0, 1 } };
  for (int sweep = 0; sweep < 6; ++sweep) {
    #pragma unroll
    for (int p = 0; p < 3; ++p) {
      #pragma unroll
      for (int q = p + 1; q < 3; ++q) {
        float apq = M[p][q];
        if (fabsf(apq) > 1e-30f) {
          float thf = (M[q][q] - M[p][p]) / (2.0f * apq);
          float tf = 1.0f / (fabsf(thf) + sqrtf(1.0f + thf * thf));
          if (thf < 0.0f) tf = -tf;
          float cf = 1.0f / sqrtf(1.0f + tf * tf);
          float sf = tf * cf;
          #pragma unroll
          for (int k = 0; k < 3; ++k) {
            float a = M[k][p], bq = M[k][q];
            M[k][p] = cf * a - sf * bq; M[k][q] = sf * a + cf * bq;
          }
          #pragma unroll
          for (int k = 0; k < 3; ++k) {
            float a = M[p][k], bq = M[q][k];
            M[p][k] = cf * a - sf * bq; M[q][k] = sf * a + cf * bq;
          }
          #pragma unroll
          for (int k = 0; k < 3; ++k) {
            float a = W3[k][p], bq = W3[k][q];
            W3[k][p] = cf * a - sf * bq; W3[k][q] = sf * a + cf * bq;
          }
        }
      }
    }
  }
  int i3 = 0; float e3 = M[0][0];
  if (M[1][1] < e3) { e3 = M[1][1]; i3 = 1; }
  if (M[2][2] < e3) { e3 = M[2][2]; i3 = 2; }
  float v3f[3];
  #pragma unroll
  for (int k = 0; k < 3; ++k) v3f[k] = W3[k][0];
  #pragma unroll
  for (int j = 1; j < 3; ++j) {
    bool take = (j == i3);
    #pragma unroll
    for (int k = 0; k < 3; ++k) v3f[k] = take ? W3[k][j] : v3f[k];
  }
  double v3[3] = { (double)v3f[0], (double)v3f[1], (double)v3f[2] };
  double Fv[3];
  #pragma unroll
  for (int i = 0; i < 3; ++i) Fv[i] = F[i][0] * v3[0] + F[i][1] * v3[1] + F[i][2] * v3[2];
  double Fr[3][3];
  #pragma unroll
  for (int i = 0; i < 3; ++i)
    #pragma unroll
    for (int j = 0; j < 3; ++j) Fr[i][j] = F[i][j] - Fv[i] * v3[j];

  // out = T2^T @ Fr @ T1
  double s1 = Tpall[0 * NPROB + prob], cx1 = Tpall[1 * NPROB + prob], cy1 = Tpall[2 * NPROB + prob];
  double s2 = Tpall[3 * NPROB + prob], cx2 = Tpall[4 * NPROB + prob], cy2 = Tpall[5 * NPROB + prob];
  double B1[3][3];
  #pragma unroll
  for (int i = 0; i < 3; ++i) {
    B1[i][0] = Fr[i][0] * s1;
    B1[i][1] = Fr[i][1] * s1;
    B1[i][2] = -Fr[i][0] * s1 * cx1 - Fr[i][1] * s1 * cy1 + Fr[i][2];
  }
  double O[3][3];
  #pragma unroll
  for (int l = 0; l < 3; ++l) {
    O[0][l] = s2 * B1[0][l];
    O[1][l] = s2 * B1[1][l];
    O[2][l] = -cx2 * s2 * B1[0][l] - cy2 * s2 * B1[1][l] + B1[2][l];
  }
  float* dst;
  if (prob < NB)            dst = dout + OFF_OUT  + prob * 9;
  else if (prob < 2 * NB)   dst = dout + OFF_OUTK + (prob - NB) * 9;
  else                      dst = dout + OFF_OUTS + (size_t)(prob - 2 * NB) * 9;
  #pragma unroll
  for (int i = 0; i < 3; ++i)
    #pragma unroll
    for (int j = 0; j < 3; ++j) dst[i * 3 + j] = (float)O[i][j];
}

// -------------------------------------------------------------- residual fn
__device__ inline double resid_point(double s1, double cx1, double cy1,
                                     double s2, double cx2, double cy2,
                                     float x1, float y1, float x2, float y2,
                                     float w, const double* __restrict__ v) {
  double p1x = s1 * ((double)x1 - cx1), p1y = s1 * ((double)y1 - cy1);
  double p2x = s2 * ((double)x2 - cx2), p2y = s2 * ((double)y2 - cy2);
  double f0 = p2x * p1x, f1 = p2x * p1y, f2 = p2x;
  double f3 = p2y * p1x, f4 = p2y * p1y, f5 = p2y;
  double f6 = p1x, f7 = p1y, f8 = 1.0;
  double n2 = f0 * f0 + f1 * f1 + f2 * f2 + f3 * f3 + f4 * f4 + f5 * f5 +
              f6 * f6 + f7 * f7 + f8 * f8;
  double sc = (double)w / sqrt(n2);
  double dt = f0 * v[0] + f1 * v[1] + f2 * v[2] + f3 * v[3] + f4 * v[4] +
              f5 * v[5] + f6 * v[6] + f7 * v[7] + f8 * v[8];
  return sc * dt;
}

// --------------------------------------- K4: tail = resid + resk + w_accu
__global__ __launch_bounds__(256) void tail_kernel(
    const float* __restrict__ pts1, const float* __restrict__ pts2,
    const float* __restrict__ wv, const int* __restrict__ topkidx,
    const int* __restrict__ sampled, const double* __restrict__ Tpall,
    const double* __restrict__ vall, float* __restrict__ dout) {
  const int bid = blockIdx.x, tid = threadIdx.x;
  if (bid < NB * (NPTS / 256)) {
    const int b = bid >> 5;
    const int n = (bid & 31) * 256 + tid;
    double Tp[6], v[9];
    #pragma unroll
    for (int j = 0; j < 6; ++j) Tp[j] = Tpall[(size_t)j * NPROB + b];
    #pragma unroll
    for (int j = 0; j < 9; ++j) v[j] = vall[(size_t)j * NPROB + b];
    const float* P1 = pts1 + ((size_t)b * NPTS + n) * 3;
    const float* P2 = pts2 + ((size_t)b * NPTS + n) * 3;
    float w = wv[(size_t)b * NPTS + n];
    double r = resid_point(Tp[0], Tp[1], Tp[2], Tp[3], Tp[4], Tp[5],
                           P1[0], P1[1], P2[0], P2[1], w, v);
    dout[OFF_RES + (size_t)b * NPTS + n] = (float)r;
    return;
  }
  const int b = bid - NB * (NPTS / 256);
  if (tid < TOPKN) {
    const int prob = NB + b;
    double Tp[6], v[9];
    #pragma unroll
    for (int j = 0; j < 6; ++j) Tp[j] = Tpall[(size_t)j * NPROB + prob];
    #pragma unroll
    for (int j = 0; j < 9; ++j) v[j] = vall[(size_t)j * NPROB + prob];
    int n = topkidx[b * TOPKN + tid];
    const float* P1 = pts1 + ((size_t)b * NPTS + n) * 3;
    const float* P2 = pts2 + ((size_t)b * NPTS + n) * 3;
    float w = wv[(size_t)b * NPTS + n];
    double r = resid_point(Tp[0], Tp[1], Tp[2], Tp[3], Tp[4], Tp[5],
                           P1[0], P1[1], P2[0], P2[1], w, v);
    dout[OFF_RESK + b * TOPKN + tid] = (float)r;
  }
  __shared__ double ssum[256];
  double prod = 0.0;
  if (tid < NSAMP) {
    const int* idx = sampled + ((size_t)b * NSAMP + tid) * TOPKN;
    prod = 1.0;
    #pragma unroll
    for (int k = 0; k < TOPKN; ++k)
      prod *= (double)wv[(size_t)b * NPTS + idx[k]] * 1000.0;
  }
  ssum[tid] = prod;
  __syncthreads();
  for (int off = 128; off > 0; off >>= 1) {
    if (tid < off) ssum[tid] += ssum[tid + off];
    __syncthreads();
  }
  double tot = ssum[0];
  if (tid < NSAMP) dout[OFF_WACC + b * NSAMP + tid] = (float)(prod / (tot + 1e-10));
}

// ----------------------------------------------------------------- launcher
extern "C" void kernel_launch(void* const* d_in, const int* in_sizes, int n_in,
                              void* d_out, int out_size, void* d_ws, size_t ws_size,
                              hipStream_t stream) {
  const float* pts1   = (const float*)d_in[0];
  const float* pts2   = (const float*)d_in[1];
  const float* wv     = (const float*)d_in[2];
  const int* un       = (const int*)d_in[3];
  const int* sampled  = (const int*)d_in[4];
  float* dout = (float*)d_out;
  char* ws = (char*)d_ws;
  double* Gall   = (double*)(ws + WS_G);
  double* Tpall  = (double*)(ws + WS_TP);
  double* vall   = (double*)(ws + WS_V);
  int*    topkix = (int*)(ws + WS_TOPK);

  prep_kernel<<<2 * NB, 1024, 0, stream>>>(pts1, pts2, wv, un, topkix, Gall, Tpall);
  small_g_kernel<<<(NB + NB * NSAMP + 255) / 256, 256, 0, stream>>>(
      pts1, pts2, wv, topkix, sampled, Gall, Tpall);
  solve_kernel<<<NPROB / 64, 128, 0, stream>>>(Gall, Tpall, vall, dout);
  tail_kernel<<<NB * (NPTS / 256) + NB, 256, 0, stream>>>(
      pts1, pts2, wv, topkix, sampled, Tpall, vall, dout);
}

// Round 13
// 183.376 us; speedup vs baseline: 1.2611x; 1.2611x over previous
//
#include <hip/hip_runtime.h>
#include <math.h>

#define NPTS   8192
#define NB     128
#define TOPKN  20
#define NSAMP  100
#define NPROB  (NB + NB + NB * NSAMP)   // 13056
#define SQRT2C 1.4142

// output element offsets (float32)
#define OFF_OUT  0
#define OFF_RES  1152
#define OFF_OUTK 1049728
#define OFF_RESK 1050880
#define OFF_OUTS 1053440
#define OFF_WACC 1168640

// workspace byte offsets (SoA: G[45][NPROB], Tp[6][NPROB], v[9][NPROB])
#define WS_G    0
#define WS_TP   4700160
#define WS_V    5326848
#define WS_TOPK 6266880

// upper-triangle index for 9x9
__device__ __forceinline__ constexpr int tri9(int i, int j) {
  int a = i < j ? i : j;
  int b = i < j ? j : i;
  return a * 9 - a * (a - 1) / 2 + (b - a);
}

// --------------------------------------------- K1: prep (topk ∥ main G)
__global__ __launch_bounds__(1024) void prep_kernel(
    const float* __restrict__ pts1, const float* __restrict__ pts2,
    const float* __restrict__ wv, const int* __restrict__ un,
    int* __restrict__ topkidx, double* __restrict__ Gall,
    double* __restrict__ Tpall) {
  __shared__ float sw[NPTS];
  __shared__ float r16a[16], r16b[16], r16c[16], r16d[16];
  __shared__ int   i16[16];
  __shared__ double sred[16][45];
  __shared__ float sbc[6];
  const int tid = threadIdx.x, lane = tid & 63, wid = tid >> 6;

  if (blockIdx.x < NB) {
    const int b = blockIdx.x;
    const int m = un[b];
    const int mlim = (m + 1023) & ~1023;
    for (int n = tid; n < mlim; n += 1024)
      sw[n] = (n < m) ? wv[(size_t)b * NPTS + n] : -INFINITY;
    __syncthreads();
    for (int k = 0; k < TOPKN; ++k) {
      float best = -INFINITY; int bi = 0x7fffffff;
      for (int n = tid; n < mlim; n += 1024) {
        float v = sw[n];
        if (v > best) { best = v; bi = n; }
      }
      #pragma unroll
      for (int off = 32; off > 0; off >>= 1) {
        float ov = __shfl_down(best, off);
        int   oi = __shfl_down(bi, off);
        if (ov > best || (ov == best && oi < bi)) { best = ov; bi = oi; }
      }
      if (lane == 0) { r16a[wid] = best; i16[wid] = bi; }
      __syncthreads();
      if (wid == 0) {
        float v = (lane < 16) ? r16a[lane] : -INFINITY;
        int  ix = (lane < 16) ? i16[lane] : 0x7fffffff;
        #pragma unroll
        for (int off = 8; off > 0; off >>= 1) {
          float ov = __shfl_down(v, off);
          int   oi = __shfl_down(ix, off);
          if (ov > v || (ov == v && oi < ix)) { v = ov; ix = oi; }
        }
        if (lane == 0) { topkidx[b * TOPKN + k] = ix; sw[ix] = -INFINITY; }
      }
      __syncthreads();
    }
    return;
  }

  // ---------------- stats + Gram (f32, register-staged) ----------------
  const int b = blockIdx.x - NB;
  const float* P1 = pts1 + (size_t)b * NPTS * 3;
  const float* P2 = pts2 + (size_t)b * NPTS * 3;
  const float* W  = wv   + (size_t)b * NPTS;

  float x1[8], y1[8], x2[8], y2[8], ww8[8];
  #pragma unroll
  for (int i = 0; i < 8; ++i) {
    const int n = tid + i * 1024;
    x1[i] = P1[n * 3]; y1[i] = P1[n * 3 + 1];
    x2[i] = P2[n * 3]; y2[i] = P2[n * 3 + 1];
    ww8[i] = W[n];
  }

  float sx1 = 0, sy1 = 0, sx2 = 0, sy2 = 0;
  #pragma unroll
  for (int i = 0; i < 8; ++i) { sx1 += x1[i]; sy1 += y1[i]; sx2 += x2[i]; sy2 += y2[i]; }
  #pragma unroll
  for (int off = 32; off > 0; off >>= 1) {
    sx1 += __shfl_down(sx1, off); sy1 += __shfl_down(sy1, off);
    sx2 += __shfl_down(sx2, off); sy2 += __shfl_down(sy2, off);
  }
  if (lane == 0) { r16a[wid] = sx1; r16b[wid] = sy1; r16c[wid] = sx2; r16d[wid] = sy2; }
  __syncthreads();
  if (wid == 0) {
    float a = (lane < 16) ? r16a[lane] : 0.f;
    float bb = (lane < 16) ? r16b[lane] : 0.f;
    float c = (lane < 16) ? r16c[lane] : 0.f;
    float d = (lane < 16) ? r16d[lane] : 0.f;
    #pragma unroll
    for (int off = 8; off > 0; off >>= 1) {
      a += __shfl_down(a, off); bb += __shfl_down(bb, off);
      c += __shfl_down(c, off); d += __shfl_down(d, off);
    }
    if (lane == 0) {
      sbc[0] = a / NPTS; sbc[1] = bb / NPTS; sbc[2] = c / NPTS; sbc[3] = d / NPTS;
    }
  }
  __syncthreads();
  const float cx1 = sbc[0], cy1 = sbc[1], cx2 = sbc[2], cy2 = sbc[3];

  float d1 = 0, d2 = 0;
  #pragma unroll
  for (int i = 0; i < 8; ++i) {
    float ax = x1[i] - cx1, ay = y1[i] - cy1;
    float bx = x2[i] - cx2, by = y2[i] - cy2;
    d1 += sqrtf(ax * ax + ay * ay);
    d2 += sqrtf(bx * bx + by * by);
  }
  #pragma unroll
  for (int off = 32; off > 0; off >>= 1) { d1 += __shfl_down(d1, off); d2 += __shfl_down(d2, off); }
  __syncthreads();
  if (lane == 0) { r16a[wid] = d1; r16b[wid] = d2; }
  __syncthreads();
  if (wid == 0) {
    float a = (lane < 16) ? r16a[lane] : 0.f;
    float bb = (lane < 16) ? r16b[lane] : 0.f;
    #pragma unroll
    for (int off = 8; off > 0; off >>= 1) { a += __shfl_down(a, off); bb += __shfl_down(bb, off); }
    if (lane == 0) {
      sbc[4] = (float)SQRT2C / (a / NPTS);
      sbc[5] = (float)SQRT2C / (bb / NPTS);
    }
  }
  __syncthreads();
  const float s1 = sbc[4], s2 = sbc[5];

  float g[45];
  #pragma unroll
  for (int i = 0; i < 45; ++i) g[i] = 0.f;
  #pragma unroll
  for (int i = 0; i < 8; ++i) {
    float p1x = s1 * (x1[i] - cx1), p1y = s1 * (y1[i] - cy1);
    float p2x = s2 * (x2[i] - cx2), p2y = s2 * (y2[i] - cy2);
    float f[9] = { p2x * p1x, p2x * p1y, p2x,
                   p2y * p1x, p2y * p1y, p2y,
                   p1x, p1y, 1.f };
    float n2 = 0.f;
    #pragma unroll
    for (int j = 0; j < 9; ++j) n2 += f[j] * f[j];
    float sc = ww8[i] / sqrtf(n2);
    #pragma unroll
    for (int j = 0; j < 9; ++j) f[j] *= sc;
    int t = 0;
    #pragma unroll
    for (int a = 0; a < 9; ++a)
      #pragma unroll
      for (int c = a; c < 9; ++c) { g[t] += f[a] * f[c]; ++t; }
  }
  #pragma unroll
  for (int t = 0; t < 45; ++t) {
    float v = g[t];
    #pragma unroll
    for (int off = 32; off > 0; off >>= 1) v += __shfl_down(v, off);
    if (lane == 0) sred[wid][t] = (double)v;
  }
  __syncthreads();
  if (tid < 45) {
    double a = 0;
    #pragma unroll
    for (int w = 0; w < 16; ++w) a += sred[w][tid];
    Gall[(size_t)tid * NPROB + b] = a;
  }
  if (tid == 0) {
    Tpall[0 * NPROB + b] = (double)s1;  Tpall[1 * NPROB + b] = (double)cx1;
    Tpall[2 * NPROB + b] = (double)cy1; Tpall[3 * NPROB + b] = (double)s2;
    Tpall[4 * NPROB + b] = (double)cx2; Tpall[5 * NPROB + b] = (double)cy2;
  }
}

// ------------------------------------------------- K2: small (20-pt) problems
__global__ __launch_bounds__(256) void small_g_kernel(
    const float* __restrict__ pts1, const float* __restrict__ pts2,
    const float* __restrict__ wv, const int* __restrict__ topkidx,
    const int* __restrict__ sampled, double* __restrict__ Gall,
    double* __restrict__ Tpall) {
  const int p = blockIdx.x * blockDim.x + threadIdx.x;
  if (p >= NB + NB * NSAMP) return;
  const int prob = NB + p;
  int b; const int* idx;
  if (p < NB) { b = p; idx = topkidx + p * TOPKN; }
  else { int q = p - NB; b = q / NSAMP; idx = sampled + (size_t)q * TOPKN; }
  const float* P1 = pts1 + (size_t)b * NPTS * 3;
  const float* P2 = pts2 + (size_t)b * NPTS * 3;
  const float* W  = wv   + (size_t)b * NPTS;

  float x1[TOPKN], y1[TOPKN], x2[TOPKN], y2[TOPKN], ww[TOPKN];
  #pragma unroll
  for (int k = 0; k < TOPKN; ++k) {
    int n = idx[k];
    x1[k] = P1[n * 3]; y1[k] = P1[n * 3 + 1];
    x2[k] = P2[n * 3]; y2[k] = P2[n * 3 + 1];
    ww[k] = W[n];
  }
  float cx1 = 0, cy1 = 0, cx2 = 0, cy2 = 0;
  #pragma unroll
  for (int k = 0; k < TOPKN; ++k) { cx1 += x1[k]; cy1 += y1[k]; cx2 += x2[k]; cy2 += y2[k]; }
  cx1 /= TOPKN; cy1 /= TOPKN; cx2 /= TOPKN; cy2 /= TOPKN;
  float d1 = 0, d2 = 0;
  #pragma unroll
  for (int k = 0; k < TOPKN; ++k) {
    float ax = x1[k] - cx1, ay = y1[k] - cy1; d1 += sqrtf(ax * ax + ay * ay);
    float bx = x2[k] - cx2, by = y2[k] - cy2; d2 += sqrtf(bx * bx + by * by);
  }
  const float s1 = (float)SQRT2C / (d1 / TOPKN), s2 = (float)SQRT2C / (d2 / TOPKN);

  float g[45];
  #pragma unroll
  for (int i = 0; i < 45; ++i) g[i] = 0.f;
  #pragma unroll
  for (int k = 0; k < TOPKN; ++k) {
    float p1x = s1 * (x1[k] - cx1), p1y = s1 * (y1[k] - cy1);
    float p2x = s2 * (x2[k] - cx2), p2y = s2 * (y2[k] - cy2);
    float f[9] = { p2x * p1x, p2x * p1y, p2x,
                   p2y * p1x, p2y * p1y, p2y,
                   p1x, p1y, 1.f };
    float n2 = 0.f;
    #pragma unroll
    for (int i = 0; i < 9; ++i) n2 += f[i] * f[i];
    float sc = ww[k] / sqrtf(n2);
    #pragma unroll
    for (int i = 0; i < 9; ++i) f[i] *= sc;
    int t = 0;
    #pragma unroll
    for (int i = 0; i < 9; ++i)
      #pragma unroll
      for (int j = i; j < 9; ++j) { g[t] += f[i] * f[j]; ++t; }
  }
  #pragma unroll
  for (int i = 0; i < 45; ++i) Gall[(size_t)i * NPROB + prob] = (double)g[i];
  Tpall[0 * NPROB + prob] = (double)s1;  Tpall[1 * NPROB + prob] = (double)cx1;
  Tpall[2 * NPROB + prob] = (double)cy1; Tpall[3 * NPROB + prob] = (double)s2;
  Tpall[4 * NPROB + prob] = (double)cx2; Tpall[5 * NPROB + prob] = (double)cy2;
}

// ---------------------------------------------------------------- K3: solve
// f32 Jacobi, one thread/problem (r11 structure — wave-split reverted).
// Rotation params use single-instruction native rcp/rsq/sqrt: the IEEE
// div/sqrt expansions (~300 serial cyc/rotation) were the measured
// bottleneck (r10->r11: halving update work moved dur only 4%).
__global__ __launch_bounds__(64, 1) void solve_kernel(
    const double* __restrict__ Gall, const double* __restrict__ Tpall,
    double* __restrict__ vall, float* __restrict__ dout) {
  const int prob = blockIdx.x * 64 + threadIdx.x;
  if (prob >= NPROB) return;

  float g[45];
  #pragma unroll
  for (int i = 0; i < 45; ++i) g[i] = (float)Gall[(size_t)i * NPROB + prob];

  float Vf[9][9];
  #pragma unroll
  for (int i = 0; i < 9; ++i)
    #pragma unroll
    for (int j = 0; j < 9; ++j) Vf[i][j] = (i == j) ? 1.0f : 0.0f;

  for (int sweep = 0; sweep < 5; ++sweep) {
    #pragma unroll
    for (int p = 0; p < 9; ++p) {
      #pragma unroll
      for (int q = p + 1; q < 9; ++q) {
        float apq = g[tri9(p, q)];
        if (fabsf(apq) > 1e-30f) {
          float app = g[tri9(p, p)], aqq = g[tri9(q, q)];
          float thf = (aqq - app) * 0.5f * __builtin_amdgcn_rcpf(apq);
          float rr  = __builtin_amdgcn_sqrtf(1.0f + thf * thf);
          float tf  = __builtin_amdgcn_rcpf(fabsf(thf) + rr);
          if (thf < 0.0f) tf = -tf;
          float cf  = __builtin_amdgcn_rsqf(1.0f + tf * tf);
          float sf  = tf * cf;
          float tauf = sf * __builtin_amdgcn_rcpf(1.0f + cf);
          g[tri9(p, p)] = app - tf * apq;
          g[tri9(q, q)] = aqq + tf * apq;
          g[tri9(p, q)] = 0.0f;
          #pragma unroll
          for (int k = 0; k < 9; ++k) {
            if (k != p && k != q) {
              float akp = g[tri9(k, p)], akq = g[tri9(k, q)];
              g[tri9(k, p)] = akp - sf * (akq + tauf * akp);
              g[tri9(k, q)] = akq + sf * (akp - tauf * akq);
            }
          }
          #pragma unroll
          for (int k = 0; k < 9; ++k) {
            float a = Vf[k][p], b2 = Vf[k][q];
            Vf[k][p] = cf * a - sf * b2;
            Vf[k][q] = sf * a + cf * b2;
          }
        }
      }
    }
  }

  // smallest eigenvalue's eigenvector
  int imin = 0; float emin = g[tri9(0, 0)];
  #pragma unroll
  for (int i = 1; i < 9; ++i) {
    float d = g[tri9(i, i)];
    if (d < emin) { emin = d; imin = i; }
  }
  double v[9];
  #pragma unroll
  for (int k = 0; k < 9; ++k) v[k] = (double)Vf[k][0];
  #pragma unroll
  for (int j = 1; j < 9; ++j) {
    bool take = (j == imin);
    #pragma unroll
    for (int k = 0; k < 9; ++k) v[k] = take ? (double)Vf[k][j] : v[k];
  }
  // normalize in f64 (kills native-approx norm drift)
  {
    double n2 = 0;
    #pragma unroll
    for (int i = 0; i < 9; ++i) n2 += v[i] * v[i];
    double inv = 1.0 / sqrt(n2);
    #pragma unroll
    for (int i = 0; i < 9; ++i) v[i] *= inv;
  }
  // sign fix
  int imax = 0; double amax = fabs(v[0]);
  #pragma unroll
  for (int i = 1; i < 9; ++i) { double a = fabs(v[i]); if (a > amax) { amax = a; imax = i; } }
  double vmax = v[0];
  #pragma unroll
  for (int i = 1; i < 9; ++i) vmax = (i == imax) ? v[i] : vmax;
  double sgn = (vmax > 0.0) ? 1.0 : ((vmax < 0.0) ? -1.0 : 0.0);
  #pragma unroll
  for (int i = 0; i < 9; ++i) v[i] *= sgn;

  #pragma unroll
  for (int i = 0; i < 9; ++i) vall[(size_t)i * NPROB + prob] = v[i];

  // rank-2 projection via f32 3x3 Jacobi on M = F^T F
  double F[3][3] = { { v[0], v[1], v[2] }, { v[3], v[4], v[5] }, { v[6], v[7], v[8] } };
  float M[3][3];
  #pragma unroll
  for (int i = 0; i < 3; ++i)
    #pragma unroll
    for (int j = 0; j < 3; ++j) {
      double acc = 0;
      #pragma unroll
      for (int k = 0; k < 3; ++k) acc += F[k][i] * F[k][j];
      M[i][j] = (float)acc;
    }
  float W3[3][3] = { { 1, 0, 0 }, { 0, 1, 0 }, { 0, 0, 1 } };
  for (int sweep = 0; sweep < 6; ++sweep) {
    #pragma unroll
    for (int p = 0; p < 3; ++p) {
      #pragma unroll
      for (int q = p + 1; q < 3; ++q) {
        float apq = M[p][q];
        if (fabsf(apq) > 1e-30f) {
          float thf = (M[q][q] - M[p][p]) * 0.5f * __builtin_amdgcn_rcpf(apq);
          float rr  = __builtin_amdgcn_sqrtf(1.0f + thf * thf);
          float tf  = __builtin_amdgcn_rcpf(fabsf(thf) + rr);
          if (thf < 0.0f) tf = -tf;
          float cf  = __builtin_amdgcn_rsqf(1.0f + tf * tf);
          float sf  = tf * cf;
          #pragma unroll
          for (int k = 0; k < 3; ++k) {
            float a = M[k][p], bq = M[k][q];
            M[k][p] = cf * a - sf * bq; M[k][q] = sf * a + cf * bq;
          }
          #pragma unroll
          for (int k = 0; k < 3; ++k) {
            float a = M[p][k], bq = M[q][k];
            M[p][k] = cf * a - sf * bq; M[q][k] = sf * a + cf * bq;
          }
          #pragma unroll
          for (int k = 0; k < 3; ++k) {
            float a = W3[k][p], bq = W3[k][q];
            W3[k][p] = cf * a - sf * bq; W3[k][q] = sf * a + cf * bq;
          }
        }
      }
    }
  }
  int i3 = 0; float e3 = M[0][0];
  if (M[1][1] < e3) { e3 = M[1][1]; i3 = 1; }
  if (M[2][2] < e3) { e3 = M[2][2]; i3 = 2; }
  float v3f[3];
  #pragma unroll
  for (int k = 0; k < 3; ++k) v3f[k] = W3[k][0];
  #pragma unroll
  for (int j = 1; j < 3; ++j) {
    bool take = (j == i3);
    #pragma unroll
    for (int k = 0; k < 3; ++k) v3f[k] = take ? W3[k][j] : v3f[k];
  }
  // normalize v3 in f64 (native-approx drift)
  double v3[3] = { (double)v3f[0], (double)v3f[1], (double)v3f[2] };
  {
    double n2 = v3[0]*v3[0] + v3[1]*v3[1] + v3[2]*v3[2];
    double inv = 1.0 / sqrt(n2);
    v3[0] *= inv; v3[1] *= inv; v3[2] *= inv;
  }
  double Fv[3];
  #pragma unroll
  for (int i = 0; i < 3; ++i) Fv[i] = F[i][0] * v3[0] + F[i][1] * v3[1] + F[i][2] * v3[2];
  double Fr[3][3];
  #pragma unroll
  for (int i = 0; i < 3; ++i)
    #pragma unroll
    for (int j = 0; j < 3; ++j) Fr[i][j] = F[i][j] - Fv[i] * v3[j];

  // out = T2^T @ Fr @ T1
  double s1 = Tpall[0 * NPROB + prob], cx1 = Tpall[1 * NPROB + prob], cy1 = Tpall[2 * NPROB + prob];
  double s2 = Tpall[3 * NPROB + prob], cx2 = Tpall[4 * NPROB + prob], cy2 = Tpall[5 * NPROB + prob];
  double B1[3][3];
  #pragma unroll
  for (int i = 0; i < 3; ++i) {
    B1[i][0] = Fr[i][0] * s1;
    B1[i][1] = Fr[i][1] * s1;
    B1[i][2] = -Fr[i][0] * s1 * cx1 - Fr[i][1] * s1 * cy1 + Fr[i][2];
  }
  double O[3][3];
  #pragma unroll
  for (int l = 0; l < 3; ++l) {
    O[0][l] = s2 * B1[0][l];
    O[1][l] = s2 * B1[1][l];
    O[2][l] = -cx2 * s2 * B1[0][l] - cy2 * s2 * B1[1][l] + B1[2][l];
  }
  float* dst;
  if (prob < NB)            dst = dout + OFF_OUT  + prob * 9;
  else if (prob < 2 * NB)   dst = dout + OFF_OUTK + (prob - NB) * 9;
  else                      dst = dout + OFF_OUTS + (size_t)(prob - 2 * NB) * 9;
  #pragma unroll
  for (int i = 0; i < 3; ++i)
    #pragma unroll
    for (int j = 0; j < 3; ++j) dst[i * 3 + j] = (float)O[i][j];
}

// -------------------------------------------------------------- residual fn
__device__ inline double resid_point(double s1, double cx1, double cy1,
                                     double s2, double cx2, double cy2,
                                     float x1, float y1, float x2, float y2,
                                     float w, const double* __restrict__ v) {
  double p1x = s1 * ((double)x1 - cx1), p1y = s1 * ((double)y1 - cy1);
  double p2x = s2 * ((double)x2 - cx2), p2y = s2 * ((double)y2 - cy2);
  double f0 = p2x * p1x, f1 = p2x * p1y, f2 = p2x;
  double f3 = p2y * p1x, f4 = p2y * p1y, f5 = p2y;
  double f6 = p1x, f7 = p1y, f8 = 1.0;
  double n2 = f0 * f0 + f1 * f1 + f2 * f2 + f3 * f3 + f4 * f4 + f5 * f5 +
              f6 * f6 + f7 * f7 + f8 * f8;
  double sc = (double)w / sqrt(n2);
  double dt = f0 * v[0] + f1 * v[1] + f2 * v[2] + f3 * v[3] + f4 * v[4] +
              f5 * v[5] + f6 * v[6] + f7 * v[7] + f8 * v[8];
  return sc * dt;
}

// --------------------------------------- K4: tail = resid + resk + w_accu
__global__ __launch_bounds__(256) void tail_kernel(
    const float* __restrict__ pts1, const float* __restrict__ pts2,
    const float* __restrict__ wv, const int* __restrict__ topkidx,
    const int* __restrict__ sampled, const double* __restrict__ Tpall,
    const double* __restrict__ vall, float* __restrict__ dout) {
  const int bid = blockIdx.x, tid = threadIdx.x;
  if (bid < NB * (NPTS / 256)) {
    const int b = bid >> 5;
    const int n = (bid & 31) * 256 + tid;
    double Tp[6], v[9];
    #pragma unroll
    for (int j = 0; j < 6; ++j) Tp[j] = Tpall[(size_t)j * NPROB + b];
    #pragma unroll
    for (int j = 0; j < 9; ++j) v[j] = vall[(size_t)j * NPROB + b];
    const float* P1 = pts1 + ((size_t)b * NPTS + n) * 3;
    const float* P2 = pts2 + ((size_t)b * NPTS + n) * 3;
    float w = wv[(size_t)b * NPTS + n];
    double r = resid_point(Tp[0], Tp[1], Tp[2], Tp[3], Tp[4], Tp[5],
                           P1[0], P1[1], P2[0], P2[1], w, v);
    dout[OFF_RES + (size_t)b * NPTS + n] = (float)r;
    return;
  }
  const int b = bid - NB * (NPTS / 256);
  if (tid < TOPKN) {
    const int prob = NB + b;
    double Tp[6], v[9];
    #pragma unroll
    for (int j = 0; j < 6; ++j) Tp[j] = Tpall[(size_t)j * NPROB + prob];
    #pragma unroll
    for (int j = 0; j < 9; ++j) v[j] = vall[(size_t)j * NPROB + prob];
    int n = topkidx[b * TOPKN + tid];
    const float* P1 = pts1 + ((size_t)b * NPTS + n) * 3;
    const float* P2 = pts2 + ((size_t)b * NPTS + n) * 3;
    float w = wv[(size_t)b * NPTS + n];
    double r = resid_point(Tp[0], Tp[1], Tp[2], Tp[3], Tp[4], Tp[5],
                           P1[0], P1[1], P2[0], P2[1], w, v);
    dout[OFF_RESK + b * TOPKN + tid] = (float)r;
  }
  __shared__ double ssum[256];
  double prod = 0.0;
  if (tid < NSAMP) {
    const int* idx = sampled + ((size_t)b * NSAMP + tid) * TOPKN;
    prod = 1.0;
    #pragma unroll
    for (int k = 0; k < TOPKN; ++k)
      prod *= (double)wv[(size_t)b * NPTS + idx[k]] * 1000.0;
  }
  ssum[tid] = prod;
  __syncthreads();
  for (int off = 128; off > 0; off >>= 1) {
    if (tid < off) ssum[tid] += ssum[tid + off];
    __syncthreads();
  }
  double tot = ssum[0];
  if (tid < NSAMP) dout[OFF_WACC + b * NSAMP + tid] = (float)(prod / (tot + 1e-10));
}

// ----------------------------------------------------------------- launcher
extern "C" void kernel_launch(void* const* d_in, const int* in_sizes, int n_in,
                              void* d_out, int out_size, void* d_ws, size_t ws_size,
                              hipStream_t stream) {
  const float* pts1   = (const float*)d_in[0];
  const float* pts2   = (const float*)d_in[1];
  const float* wv     = (const float*)d_in[2];
  const int* un       = (const int*)d_in[3];
  const int* sampled  = (const int*)d_in[4];
  float* dout = (float*)d_out;
  char* ws = (char*)d_ws;
  double* Gall   = (double*)(ws + WS_G);
  double* Tpall  = (double*)(ws + WS_TP);
  double* vall   = (double*)(ws + WS_V);
  int*    topkix = (int*)(ws + WS_TOPK);

  prep_kernel<<<2 * NB, 1024, 0, stream>>>(pts1, pts2, wv, un, topkix, Gall, Tpall);
  small_g_kernel<<<(NB + NB * NSAMP + 255) / 256, 256, 0, stream>>>(
      pts1, pts2, wv, topkix, sampled, Gall, Tpall);
  solve_kernel<<<(NPROB + 63) / 64, 64, 0, stream>>>(Gall, Tpall, vall, dout);
  tail_kernel<<<NB * (NPTS / 256) + NB, 256, 0, stream>>>(
      pts1, pts2, wv, topkix, sampled, Tpall, vall, dout);
}